// Round 9
// baseline (1806.110 us; speedup 1.0000x reference)
//
#include <hip/hip_runtime.h>

#define KNN 30
#define FDIM 64
#define HDIM 64

typedef short s8v __attribute__((ext_vector_type(8)));   // 8 bf16 bit-patterns (4 VGPR)
typedef float f4v __attribute__((ext_vector_type(4)));   // MFMA accumulator
typedef unsigned long long u64;

// round-to-nearest-even f32 -> bf16 bits
static __device__ __forceinline__ unsigned short f2bf(float f) {
  unsigned int u = __builtin_bit_cast(unsigned int, f);
  u += 0x7fffu + ((u >> 16) & 1u);
  return (unsigned short)(u >> 16);
}
static __device__ __forceinline__ float bf2f(unsigned short h) {
  unsigned int u = ((unsigned int)h) << 16;
  return __builtin_bit_cast(float, u);
}

// f32 bits -> order-preserving u32 (asc float order == asc uint order)
static __device__ __forceinline__ unsigned int f2sort(float f) {
  unsigned int u = __builtin_bit_cast(unsigned int, f);
  unsigned int m = (unsigned int)(((int)u) >> 31) | 0x80000000u;
  return u ^ m;
}

// XOR swizzle (ushort-index space): byte ^= (row&7)<<4  <=>  idx ^= (row&7)<<3
static __device__ __forceinline__ int swzi(int row, int col, int roww) {
  return (row * roww + col) ^ ((row & 7) << 3);
}

static __device__ __forceinline__ void lds_fence() {
  asm volatile("s_waitcnt lgkmcnt(0)" ::: "memory");
  __builtin_amdgcn_sched_barrier(0);
}

static __device__ __forceinline__ s8v pack8(float4 a, float4 b) {
  s8v v;
  v[0] = (short)f2bf(a.x); v[1] = (short)f2bf(a.y);
  v[2] = (short)f2bf(a.z); v[3] = (short)f2bf(a.w);
  v[4] = (short)f2bf(b.x); v[5] = (short)f2bf(b.y);
  v[6] = (short)f2bf(b.z); v[7] = (short)f2bf(b.w);
  return v;
}

// ---------------- prep: xbf = bf16(x) and sq = |x|^2 (exact f32) ----------------
__global__ __launch_bounds__(256) void prep_kernel(const float* __restrict__ x,
                                                   unsigned short* __restrict__ xbf,
                                                   float* __restrict__ sq) {
  int t = threadIdx.x;
  int r = blockIdx.x * 32 + (t >> 3);
  int sub = t & 7;
  const float* p = x + (size_t)r * FDIM + sub * 8;
  float4 a = *reinterpret_cast<const float4*>(p);
  float4 b = *reinterpret_cast<const float4*>(p + 4);
  *reinterpret_cast<s8v*>(xbf + (size_t)r * FDIM + sub * 8) = pack8(a, b);
  float s = a.x * a.x;
  s = fmaf(a.y, a.y, s); s = fmaf(a.z, a.z, s); s = fmaf(a.w, a.w, s);
  s = fmaf(b.x, b.x, s); s = fmaf(b.y, b.y, s); s = fmaf(b.z, b.z, s);
  s = fmaf(b.w, b.w, s);
  s += __shfl_xor(s, 1);
  s += __shfl_xor(s, 2);
  s += __shfl_xor(s, 4);
  if (sub == 0) sq[r] = s;
}

// ---------------- U/P precompute (layer-1 algebraic elimination) ----------------
__global__ __launch_bounds__(256) void uP_kernel(const float* __restrict__ x,
                                                 const float* __restrict__ W1,
                                                 const float* __restrict__ b1,
                                                 float* __restrict__ U,
                                                 unsigned short* __restrict__ P) {
  __shared__ __align__(16) unsigned short sWT[128 * 64];
  int t = threadIdx.x;
  for (int e = t; e < 64 * 64; e += 256) {
    int f = e >> 6, h = e & 63;
    float wa = W1[f * 64 + h];
    float wb = W1[(64 + f) * 64 + h];
    sWT[swzi(h, f, 64)] = f2bf(wa + wb);
    sWT[swzi(64 + h, f, 64)] = f2bf(wb);
  }
  __syncthreads();
  int wv = t >> 6, lane = t & 63;
  int q = lane >> 4, cl = lane & 15;
  int base = blockIdx.x * 128 + wv * 32;

  s8v af[2][2];
#pragma unroll
  for (int mt = 0; mt < 2; ++mt)
#pragma unroll
    for (int ks = 0; ks < 2; ++ks) {
      const float* px = x + (size_t)(base + mt * 16 + cl) * FDIM + ks * 32 + q * 8;
      float4 a = *reinterpret_cast<const float4*>(px);
      float4 b = *reinterpret_cast<const float4*>(px + 4);
      af[mt][ks] = pack8(a, b);
    }
  f4v acc[2][8];
#pragma unroll
  for (int nt = 0; nt < 8; ++nt) {
    float bb = (nt < 4) ? b1[nt * 16 + cl] : 0.0f;
    f4v a0 = {bb, bb, bb, bb};
    acc[0][nt] = a0;
    acc[1][nt] = a0;
  }
#pragma unroll
  for (int ks = 0; ks < 2; ++ks)
#pragma unroll
    for (int nt = 0; nt < 8; ++nt) {
      s8v wf = *reinterpret_cast<const s8v*>(&sWT[swzi(nt * 16 + cl, ks * 32 + q * 8, 64)]);
      acc[0][nt] = __builtin_amdgcn_mfma_f32_16x16x32_bf16(af[0][ks], wf, acc[0][nt], 0, 0, 0);
      acc[1][nt] = __builtin_amdgcn_mfma_f32_16x16x32_bf16(af[1][ks], wf, acc[1][nt], 0, 0, 0);
    }
#pragma unroll
  for (int mt = 0; mt < 2; ++mt)
#pragma unroll
    for (int nt = 0; nt < 8; ++nt)
#pragma unroll
      for (int i = 0; i < 4; ++i) {
        int row = base + mt * 16 + q * 4 + i;
        if (nt < 4) U[(size_t)row * 64 + nt * 16 + cl] = acc[mt][nt][i];
        else        P[(size_t)row * 64 + (nt - 4) * 16 + cl] = f2bf(acc[mt][nt][i]);
      }
}

// ---------------- fused KNN v2: two-pass streaming MFMA + threshold + exact rescan ----
// Block = 4 waves, 64 rows (one batch). B panel double-buffered in LDS (16KB), sq staged.
// Pass 1: running f32 mins over 32 subsets/row -> tau = 2nd-largest of 32 subset-mins
//   (subset-mins are row values => rank-31 of subset >= true rank-31: provable bound).
// Pass 2: recompute (bit-identical MFMA), collect d <= tau + 1.03125 into per-row pool.
// Exact fp32 rescan + rank-count select (validated R4-R8 logic). Fallback if >96 cands.
__global__ __launch_bounds__(256) void knn2_kernel(const unsigned short* __restrict__ xbf,
                                                   const float* __restrict__ x,
                                                   const float* __restrict__ sq,
                                                   int* __restrict__ idxout, int V) {
  __shared__ float sSq[2048];                              // 8KB (V==2048)
  __shared__ __align__(16) unsigned short sB[2][64 * 64];  // 16KB dbuf B panel
  __shared__ __align__(16) char sWS[4][3968];              // per-wave scratch
  __shared__ float sTau[4][16];
  __shared__ unsigned int sCnt[4][16];

  int t = threadIdx.x;
  int wv = t >> 6, lane = t & 63;
  int q = lane >> 4, cl = lane & 15;
  int Rblk = blockIdx.x * 64;
  int b = Rblk / V;
  size_t bbase = (size_t)b * V;
  const unsigned short* xbfb = xbf + bbase * FDIM;
  int Rw = Rblk + wv * 16;
  int v0w = Rw - b * V;
  int nch = V / 64;  // 32

  // stage sSq (whole batch)
  for (int o = t * 4; o < V; o += 1024)
    *reinterpret_cast<float4*>(&sSq[o]) = *reinterpret_cast<const float4*>(&sq[bbase + o]);

  // A-frags: 16 rows/wave, row index = cl, k = ks*32 + q*8
  s8v af[2];
  af[0] = *reinterpret_cast<const s8v*>(xbfb + (size_t)(v0w + cl) * FDIM + q * 8);
  af[1] = *reinterpret_cast<const s8v*>(xbfb + (size_t)(v0w + cl) * FDIM + 32 + q * 8);

  // chunk staging: thread t loads col (t>>2) of chunk, k = (t&3)*16 .. +16
  int scol = t >> 2, sk = (t & 3) * 16;
  s8v nx0, nx1;
  {
    const unsigned short* src = xbfb + (size_t)scol * FDIM + sk;
    nx0 = *reinterpret_cast<const s8v*>(src);
    nx1 = *reinterpret_cast<const s8v*>(src + 8);
    *reinterpret_cast<s8v*>(&sB[0][swzi(scol, sk, 64)]) = nx0;
    *reinterpret_cast<s8v*>(&sB[0][swzi(scol, sk + 8, 64)]) = nx1;
  }
  __syncthreads();

  const float PINF = __builtin_inff();
  float rmin[2][4] = {{PINF, PINF, PINF, PINF}, {PINF, PINF, PINF, PINF}};

  // ---- pass 1: subset mins ----
  for (int cc = 0; cc < nch; ++cc) {
    if (cc + 1 < nch) {  // issue next-chunk loads early (T14)
      const unsigned short* src = xbfb + (size_t)((cc + 1) * 64 + scol) * FDIM + sk;
      nx0 = *reinterpret_cast<const s8v*>(src);
      nx1 = *reinterpret_cast<const s8v*>(src + 8);
    }
    int buf = cc & 1;
#pragma unroll
    for (int st = 0; st < 4; ++st) {
      s8v b0 = *reinterpret_cast<const s8v*>(&sB[buf][swzi(st * 16 + cl, q * 8, 64)]);
      s8v b1 = *reinterpret_cast<const s8v*>(&sB[buf][swzi(st * 16 + cl, 32 + q * 8, 64)]);
      f4v z = {0.f, 0.f, 0.f, 0.f};
      f4v a = __builtin_amdgcn_mfma_f32_16x16x32_bf16(af[0], b0, z, 0, 0, 0);
      a = __builtin_amdgcn_mfma_f32_16x16x32_bf16(af[1], b1, a, 0, 0, 0);
      float sqv = sSq[cc * 64 + st * 16 + cl];
      int p = st & 1;
#pragma unroll
      for (int i = 0; i < 4; ++i) {
        float d = fmaf(-2.f, a[i], sqv);
        rmin[p][i] = fminf(rmin[p][i], d);
      }
    }
    if (cc + 1 < nch) {  // write-late into other buffer
      *reinterpret_cast<s8v*>(&sB[buf ^ 1][swzi(scol, sk, 64)]) = nx0;
      *reinterpret_cast<s8v*>(&sB[buf ^ 1][swzi(scol, sk + 8, 64)]) = nx1;
    }
    __syncthreads();
  }

  // ---- tau per row: 2nd-largest (lex with index) of 32 subset-mins ----
  float(*sm)[33] = reinterpret_cast<float(*)[33]>(&sWS[wv][0]);
#pragma unroll
  for (int p = 0; p < 2; ++p)
#pragma unroll
    for (int i = 0; i < 4; ++i) sm[q * 4 + i][cl * 2 + p] = rmin[p][i];
  lds_fence();
  {
    int row = lane >> 2, ch = lane & 3;
    float v1 = -PINF, v2 = -PINF;
    int c1 = -1, c2 = -1;
#pragma unroll
    for (int k = 0; k < 8; ++k) {
      int c = ch * 8 + k;
      float v = sm[row][c];
      bool g1 = (v > v1) || (v == v1 && c > c1);
      bool g2 = (v > v2) || (v == v2 && c > c2);
      if (g1) { v2 = v1; c2 = c1; v1 = v; c1 = c; }
      else if (g2) { v2 = v; c2 = c; }
    }
#pragma unroll
    for (int off = 1; off <= 2; off <<= 1) {
      float w1 = __shfl_xor(v1, off), w2 = __shfl_xor(v2, off);
      int d1 = __shfl_xor(c1, off), d2 = __shfl_xor(c2, off);
      bool a1b = (v1 > w1) || (v1 == w1 && c1 > d1);
      float lo1v = a1b ? w1 : v1; int lo1c = a1b ? d1 : c1;
      float hi1v = a1b ? v1 : w1; int hi1c = a1b ? c1 : d1;
      bool a2b = (v2 > w2) || (v2 == w2 && c2 > d2);
      float hi2v = a2b ? v2 : w2; int hi2c = a2b ? c2 : d2;
      bool s2 = (lo1v > hi2v) || (lo1v == hi2v && lo1c > hi2c);
      v1 = hi1v; c1 = hi1c;
      v2 = s2 ? lo1v : hi2v; c2 = s2 ? lo1c : hi2c;
    }
    if ((lane & 3) == 0) sTau[wv][row] = v2;
  }
  if (lane < 16) sCnt[wv][lane] = 0;
  lds_fence();
  float thr[4];
#pragma unroll
  for (int i = 0; i < 4; ++i) thr[i] = sTau[wv][q * 4 + i] + 1.03125f;

  // ---- pass 2: collect candidates ----
  unsigned short(*pool)[96] = reinterpret_cast<unsigned short(*)[96]>(&sWS[wv][0]);
  unsigned int* cnt = &sCnt[wv][0];
  {
    const unsigned short* src = xbfb + (size_t)scol * FDIM + sk;
    nx0 = *reinterpret_cast<const s8v*>(src);
    nx1 = *reinterpret_cast<const s8v*>(src + 8);
    *reinterpret_cast<s8v*>(&sB[0][swzi(scol, sk, 64)]) = nx0;
    *reinterpret_cast<s8v*>(&sB[0][swzi(scol, sk + 8, 64)]) = nx1;
  }
  __syncthreads();
  for (int cc = 0; cc < nch; ++cc) {
    if (cc + 1 < nch) {
      const unsigned short* src = xbfb + (size_t)((cc + 1) * 64 + scol) * FDIM + sk;
      nx0 = *reinterpret_cast<const s8v*>(src);
      nx1 = *reinterpret_cast<const s8v*>(src + 8);
    }
    int buf = cc & 1;
#pragma unroll
    for (int st = 0; st < 4; ++st) {
      s8v b0 = *reinterpret_cast<const s8v*>(&sB[buf][swzi(st * 16 + cl, q * 8, 64)]);
      s8v b1 = *reinterpret_cast<const s8v*>(&sB[buf][swzi(st * 16 + cl, 32 + q * 8, 64)]);
      f4v z = {0.f, 0.f, 0.f, 0.f};
      f4v a = __builtin_amdgcn_mfma_f32_16x16x32_bf16(af[0], b0, z, 0, 0, 0);
      a = __builtin_amdgcn_mfma_f32_16x16x32_bf16(af[1], b1, a, 0, 0, 0);
      int col = cc * 64 + st * 16 + cl;
      float sqv = sSq[col];
#pragma unroll
      for (int i = 0; i < 4; ++i) {
        float d = fmaf(-2.f, a[i], sqv);
        if (d <= thr[i]) {
          unsigned s = atomicAdd(&cnt[q * 4 + i], 1u);
          if (s < 96) pool[q * 4 + i][s] = (unsigned short)col;
        }
      }
    }
    if (cc + 1 < nch) {
      *reinterpret_cast<s8v*>(&sB[buf ^ 1][swzi(scol, sk, 64)]) = nx0;
      *reinterpret_cast<s8v*>(&sB[buf ^ 1][swzi(scol, sk + 8, 64)]) = nx1;
    }
    __syncthreads();
  }
  lds_fence();

  // ---- exact fp32 rescan + rank-count select, per row (wave-local) ----
  u64* pool2 = reinterpret_cast<u64*>(&sWS[wv][3072]);  // 104 u64
  int g8 = lane >> 3, sub = lane & 7;
  for (int r = 0; r < 16; ++r) {
    int cn = (int)cnt[r];
    int R = Rw + r;
    if (cn <= 96) {
      const float* xvp = x + (size_t)R * FDIM + sub * 8;
      float4 xa = *reinterpret_cast<const float4*>(xvp);
      float4 xb2 = *reinterpret_cast<const float4*>(xvp + 4);
      int rounds = (cn + 7) >> 3;
      for (int it = 0; it < rounds; ++it) {
        int c = it * 8 + g8;
        int w = pool[r][c < cn ? c : 0];
        const float* xwp = x + (bbase + (unsigned)w) * FDIM + sub * 8;
        float4 b0 = *reinterpret_cast<const float4*>(xwp);
        float4 b1 = *reinterpret_cast<const float4*>(xwp + 4);
        float dot = xa.x * b0.x;
        dot = fmaf(xa.y, b0.y, dot); dot = fmaf(xa.z, b0.z, dot);
        dot = fmaf(xa.w, b0.w, dot); dot = fmaf(xb2.x, b1.x, dot);
        dot = fmaf(xb2.y, b1.y, dot); dot = fmaf(xb2.z, b1.z, dot);
        dot = fmaf(xb2.w, b1.w, dot);
        dot += __shfl_xor(dot, 1);
        dot += __shfl_xor(dot, 2);
        dot += __shfl_xor(dot, 4);
        float dx = fmaf(-2.f, dot, sSq[w]);
        if (sub == 0 && c < cn) pool2[c] = ((u64)f2sort(dx) << 32) | (unsigned)w;
      }
      int nb = (cn + 7) & ~7;
      if (lane < nb - cn) pool2[cn + lane] = ~0ULL;
      lds_fence();
      u64 k1 = pool2[lane];
      u64 k2 = (64 + lane < nb) ? pool2[64 + lane] : ~0ULL;
      int rk1 = 0, rk2 = 0;
      for (int d0 = 0; d0 < nb; d0 += 8) {
#pragma unroll
        for (int u = 0; u < 8; ++u) {
          u64 v = pool2[d0 + u];
          rk1 += (v < k1);
          rk2 += (v < k2);
        }
      }
      if (lane < cn && rk1 >= 1 && rk1 <= KNN)
        idxout[(size_t)R * KNN + (rk1 - 1)] = (int)(unsigned)(k1 & 0xFFFFFFFFu);
      if (64 + lane < cn && rk2 >= 1 && rk2 <= KNN)
        idxout[(size_t)R * KNN + (rk2 - 1)] = (int)(unsigned)(k2 & 0xFFFFFFFFu);
      lds_fence();
    } else {
      // exhaustive exact fallback (pathological clustering only; V==2048)
      float* sXvf = reinterpret_cast<float*>(pool2);
      sXvf[lane] = x[(size_t)R * FDIM + lane];
      lds_fence();
      unsigned int sve[32];
#pragma unroll 1
      for (int rr = 0; rr < 32; ++rr) {
        int w = rr * 64 + lane;
        const float* xw = x + (bbase + (unsigned)w) * FDIM;
        float dot = 0.f;
        for (int f = 0; f < FDIM; ++f) dot = fmaf(sXvf[f], xw[f], dot);
        sve[rr] = f2sort(fmaf(-2.f, dot, sSq[w]));
      }
      unsigned removed = 0;
      for (int it = 0; it < KNN + 1; ++it) {
        u64 m2 = ~0ULL;
#pragma unroll
        for (int rr = 0; rr < 32; ++rr) {
          u64 key = ((u64)sve[rr] << 32) | (unsigned)(rr * 64 + lane);
          bool alive = ((removed >> rr) & 1u) == 0u;
          if (alive && key < m2) m2 = key;
        }
        u64 gk = m2;
#pragma unroll
        for (int off = 32; off; off >>= 1) {
          u64 o = __shfl_xor(gk, off);
          gk = (o < gk) ? o : gk;
        }
        if (it > 0 && lane == 0)
          idxout[(size_t)R * KNN + (it - 1)] = (int)(unsigned)(gk & 0xFFFFFFFFu);
#pragma unroll
        for (int rr = 0; rr < 32; ++rr) {
          u64 key = ((u64)sve[rr] << 32) | (unsigned)(rr * 64 + lane);
          if (key == gk) removed |= (1u << rr);
        }
      }
      lds_fence();
    }
  }
}

// ---------------- fused layers 2,3 + max aggregation ----------------
__global__ __launch_bounds__(256) void mlp_kernel(const float* __restrict__ U,
                                                  const unsigned short* __restrict__ P,
                                                  const int* __restrict__ idx,
                                                  const float* __restrict__ W2,
                                                  const float* __restrict__ b2,
                                                  const float* __restrict__ W3,
                                                  const float* __restrict__ b3,
                                                  float* __restrict__ out, int V) {
  __shared__ __align__(16) unsigned short sW2T[HDIM * HDIM];
  __shared__ __align__(16) unsigned short sW3T[HDIM * HDIM];
  __shared__ __align__(16) unsigned short sScr[4][2048];
  int t = threadIdx.x;
  for (int e = t; e < HDIM * HDIM; e += 256) {
    int i = e >> 6, j = e & 63;
    sW2T[swzi(j, i, 64)] = f2bf(W2[e]);
    int s = (i & 15) * 4 + (i >> 4);
    sW3T[swzi(j, s, 64)] = f2bf(W3[e]);
  }
  __syncthreads();

  int wv = t >> 6, lane = t & 63;
  int q = lane >> 4, cl = lane & 15;
  int g = lane >> 3, sub = lane & 7;
  unsigned short* scr = &sScr[wv][0];
  float bias2[4], bias3[4];
#pragma unroll
  for (int nt = 0; nt < 4; ++nt) {
    bias2[nt] = b2[nt * 16 + cl];
    bias3[nt] = b3[nt * 16 + cl];
  }

  for (int vi = 0; vi < 4; ++vi) {
    int v = blockIdx.x * 16 + wv * 4 + vi;
    int b = v / V;
    size_t bbase = (size_t)b * V;
    int myidx = (lane < KNN) ? idx[(size_t)v * KNN + lane] : 0;
    const float* up = U + (size_t)v * 64 + sub * 8;
    float4 u0 = *reinterpret_cast<const float4*>(up);
    float4 u1 = *reinterpret_cast<const float4*>(up + 4);
    float uu[8] = {u0.x, u0.y, u0.z, u0.w, u1.x, u1.y, u1.z, u1.w};

#pragma unroll
    for (int it = 0; it < 4; ++it) {
      int r = it * 8 + g;
      int kk = (r < KNN) ? r : (KNN - 1);
      int nb = __shfl(myidx, kk);
      const unsigned short* pp = P + (bbase + (unsigned int)nb) * 64 + sub * 8;
      s8v p8 = *reinterpret_cast<const s8v*>(pp);
      s8v hv;
#pragma unroll
      for (int j = 0; j < 8; ++j) {
        float f = uu[j] - bf2f((unsigned short)p8[j]);
        hv[j] = (short)f2bf(fmaxf(f, 0.0f));
      }
      *reinterpret_cast<s8v*>(&scr[swzi(r, sub * 8, 64)]) = hv;
    }
    lds_fence();

    s8v af2[2][2];
#pragma unroll
    for (int mt = 0; mt < 2; ++mt)
#pragma unroll
      for (int ks = 0; ks < 2; ++ks)
        af2[mt][ks] = *reinterpret_cast<const s8v*>(&scr[swzi(mt * 16 + cl, ks * 32 + q * 8, 64)]);
    f4v acc2[2][4];
#pragma unroll
    for (int mt = 0; mt < 2; ++mt)
#pragma unroll
      for (int nt = 0; nt < 4; ++nt) {
        f4v a0 = {bias2[nt], bias2[nt], bias2[nt], bias2[nt]};
        acc2[mt][nt] = a0;
      }
#pragma unroll
    for (int ks = 0; ks < 2; ++ks)
#pragma unroll
      for (int nt = 0; nt < 4; ++nt) {
        s8v wf = *reinterpret_cast<const s8v*>(&sW2T[swzi(nt * 16 + cl, ks * 32 + q * 8, 64)]);
        acc2[0][nt] = __builtin_amdgcn_mfma_f32_16x16x32_bf16(af2[0][ks], wf, acc2[0][nt], 0, 0, 0);
        acc2[1][nt] = __builtin_amdgcn_mfma_f32_16x16x32_bf16(af2[1][ks], wf, acc2[1][nt], 0, 0, 0);
      }
    lds_fence();
#pragma unroll
    for (int mt = 0; mt < 2; ++mt)
#pragma unroll
      for (int i = 0; i < 4; ++i) {
        int m = mt * 16 + q * 4 + i;
        u64 pk = 0;
#pragma unroll
        for (int nt = 0; nt < 4; ++nt) {
          u64 hb = f2bf(fmaxf(acc2[mt][nt][i], 0.0f));
          pk |= hb << (16 * nt);
        }
        *reinterpret_cast<u64*>(&scr[swzi(m, cl * 4, 64)]) = pk;
      }
    lds_fence();

    s8v af3[2][2];
#pragma unroll
    for (int mt = 0; mt < 2; ++mt)
#pragma unroll
      for (int ks = 0; ks < 2; ++ks)
        af3[mt][ks] = *reinterpret_cast<const s8v*>(&scr[swzi(mt * 16 + cl, ks * 32 + q * 8, 64)]);
    f4v acc3[2][4];
#pragma unroll
    for (int mt = 0; mt < 2; ++mt)
#pragma unroll
      for (int nt = 0; nt < 4; ++nt) {
        f4v a0 = {bias3[nt], bias3[nt], bias3[nt], bias3[nt]};
        acc3[mt][nt] = a0;
      }
#pragma unroll
    for (int ks = 0; ks < 2; ++ks)
#pragma unroll
      for (int nt = 0; nt < 4; ++nt) {
        s8v wf = *reinterpret_cast<const s8v*>(&sW3T[swzi(nt * 16 + cl, ks * 32 + q * 8, 64)]);
        acc3[0][nt] = __builtin_amdgcn_mfma_f32_16x16x32_bf16(af3[0][ks], wf, acc3[0][nt], 0, 0, 0);
        acc3[1][nt] = __builtin_amdgcn_mfma_f32_16x16x32_bf16(af3[1][ks], wf, acc3[1][nt], 0, 0, 0);
      }

    float m[4] = {0.0f, 0.0f, 0.0f, 0.0f};
#pragma unroll
    for (int nt = 0; nt < 4; ++nt)
#pragma unroll
      for (int mt = 0; mt < 2; ++mt)
#pragma unroll
        for (int i = 0; i < 4; ++i) m[nt] = fmaxf(m[nt], acc3[mt][nt][i]);
#pragma unroll
    for (int nt = 0; nt < 4; ++nt) {
      m[nt] = fmaxf(m[nt], __shfl_xor(m[nt], 16));
      m[nt] = fmaxf(m[nt], __shfl_xor(m[nt], 32));
    }
    float outv = (q == 0) ? m[0] : (q == 1) ? m[1] : (q == 2) ? m[2] : m[3];
    out[(size_t)v * HDIM + lane] = outv;
  }
}

extern "C" void kernel_launch(void* const* d_in, const int* in_sizes, int n_in,
                              void* d_out, int out_size, void* d_ws, size_t ws_size,
                              hipStream_t stream) {
  const float* x  = (const float*)d_in[0];
  const float* W1 = (const float*)d_in[2];
  const float* b1 = (const float*)d_in[3];
  const float* W2 = (const float*)d_in[4];
  const float* b2 = (const float*)d_in[5];
  const float* W3 = (const float*)d_in[6];
  const float* b3 = (const float*)d_in[7];
  float* out = (float*)d_out;
  int N = in_sizes[0] / FDIM;      // 32768
  int B = in_sizes[1] - 1;         // 16
  int V = N / B;                   // 2048

  char* ws = (char*)d_ws;
  float* sqbuf = (float*)ws;
  size_t off = (size_t)N * sizeof(float);
  int* idxbuf = (int*)(ws + off);
  off += (size_t)N * KNN * sizeof(int);
  off = (off + 255) & ~(size_t)255;
  float* Ubuf = (float*)(ws + off);
  off += (size_t)N * 64 * sizeof(float);
  unsigned short* Pbuf = (unsigned short*)(ws + off);
  off += (size_t)N * 64 * sizeof(unsigned short);
  off = (off + 255) & ~(size_t)255;
  unsigned short* xbfbuf = (unsigned short*)(ws + off);

  prep_kernel<<<N / 32, 256, 0, stream>>>(x, xbfbuf, sqbuf);
  uP_kernel<<<N / 128, 256, 0, stream>>>(x, W1, b1, Ubuf, Pbuf);
  knn2_kernel<<<N / 64, 256, 0, stream>>>(xbfbuf, x, sqbuf, idxbuf, V);
  mlp_kernel<<<N / 16, 256, 0, stream>>>(Ubuf, Pbuf, idxbuf, W2, b2, W3, b3, out, V);
}

// Round 10
// 234.706 us; speedup vs baseline: 7.6952x; 7.6952x over previous
//
#include <hip/hip_runtime.h>

#define KNN 30
#define FDIM 64
#define HDIM 64

typedef short s8v __attribute__((ext_vector_type(8)));   // 8 bf16 bit-patterns (4 VGPR)
typedef float f4v __attribute__((ext_vector_type(4)));   // MFMA accumulator
typedef unsigned long long u64;

// round-to-nearest-even f32 -> bf16 bits
static __device__ __forceinline__ unsigned short f2bf(float f) {
  unsigned int u = __builtin_bit_cast(unsigned int, f);
  u += 0x7fffu + ((u >> 16) & 1u);
  return (unsigned short)(u >> 16);
}
static __device__ __forceinline__ float bf2f(unsigned short h) {
  unsigned int u = ((unsigned int)h) << 16;
  return __builtin_bit_cast(float, u);
}

// f32 bits -> order-preserving u32 (asc float order == asc uint order)
static __device__ __forceinline__ unsigned int f2sort(float f) {
  unsigned int u = __builtin_bit_cast(unsigned int, f);
  unsigned int m = (unsigned int)(((int)u) >> 31) | 0x80000000u;
  return u ^ m;
}

// XOR swizzle (ushort-index space): byte ^= (row&7)<<4  <=>  idx ^= (row&7)<<3
static __device__ __forceinline__ int swzi(int row, int col, int roww) {
  return (row * roww + col) ^ ((row & 7) << 3);
}

static __device__ __forceinline__ void lds_fence() {
  asm volatile("s_waitcnt lgkmcnt(0)" ::: "memory");
  __builtin_amdgcn_sched_barrier(0);
}

static __device__ __forceinline__ s8v pack8(float4 a, float4 b) {
  s8v v;
  v[0] = (short)f2bf(a.x); v[1] = (short)f2bf(a.y);
  v[2] = (short)f2bf(a.z); v[3] = (short)f2bf(a.w);
  v[4] = (short)f2bf(b.x); v[5] = (short)f2bf(b.y);
  v[6] = (short)f2bf(b.z); v[7] = (short)f2bf(b.w);
  return v;
}

// ---------------- prep: xbf = bf16(x) and sq = |x|^2 (exact f32) ----------------
__global__ __launch_bounds__(256) void prep_kernel(const float* __restrict__ x,
                                                   unsigned short* __restrict__ xbf,
                                                   float* __restrict__ sq) {
  int t = threadIdx.x;
  int r = blockIdx.x * 32 + (t >> 3);
  int sub = t & 7;
  const float* p = x + (size_t)r * FDIM + sub * 8;
  float4 a = *reinterpret_cast<const float4*>(p);
  float4 b = *reinterpret_cast<const float4*>(p + 4);
  *reinterpret_cast<s8v*>(xbf + (size_t)r * FDIM + sub * 8) = pack8(a, b);
  float s = a.x * a.x;
  s = fmaf(a.y, a.y, s); s = fmaf(a.z, a.z, s); s = fmaf(a.w, a.w, s);
  s = fmaf(b.x, b.x, s); s = fmaf(b.y, b.y, s); s = fmaf(b.z, b.z, s);
  s = fmaf(b.w, b.w, s);
  s += __shfl_xor(s, 1);
  s += __shfl_xor(s, 2);
  s += __shfl_xor(s, 4);
  if (sub == 0) sq[r] = s;
}

// ---------------- U/P precompute (layer-1 algebraic elimination) ----------------
__global__ __launch_bounds__(256) void uP_kernel(const float* __restrict__ x,
                                                 const float* __restrict__ W1,
                                                 const float* __restrict__ b1,
                                                 float* __restrict__ U,
                                                 unsigned short* __restrict__ P) {
  __shared__ __align__(16) unsigned short sWT[128 * 64];
  int t = threadIdx.x;
  for (int e = t; e < 64 * 64; e += 256) {
    int f = e >> 6, h = e & 63;
    float wa = W1[f * 64 + h];
    float wb = W1[(64 + f) * 64 + h];
    sWT[swzi(h, f, 64)] = f2bf(wa + wb);
    sWT[swzi(64 + h, f, 64)] = f2bf(wb);
  }
  __syncthreads();
  int wv = t >> 6, lane = t & 63;
  int q = lane >> 4, cl = lane & 15;
  int base = blockIdx.x * 128 + wv * 32;

  s8v af[2][2];
#pragma unroll
  for (int mt = 0; mt < 2; ++mt)
#pragma unroll
    for (int ks = 0; ks < 2; ++ks) {
      const float* px = x + (size_t)(base + mt * 16 + cl) * FDIM + ks * 32 + q * 8;
      float4 a = *reinterpret_cast<const float4*>(px);
      float4 b = *reinterpret_cast<const float4*>(px + 4);
      af[mt][ks] = pack8(a, b);
    }
  f4v acc[2][8];
#pragma unroll
  for (int nt = 0; nt < 8; ++nt) {
    float bb = (nt < 4) ? b1[nt * 16 + cl] : 0.0f;
    f4v a0 = {bb, bb, bb, bb};
    acc[0][nt] = a0;
    acc[1][nt] = a0;
  }
#pragma unroll
  for (int ks = 0; ks < 2; ++ks)
#pragma unroll
    for (int nt = 0; nt < 8; ++nt) {
      s8v wf = *reinterpret_cast<const s8v*>(&sWT[swzi(nt * 16 + cl, ks * 32 + q * 8, 64)]);
      acc[0][nt] = __builtin_amdgcn_mfma_f32_16x16x32_bf16(af[0][ks], wf, acc[0][nt], 0, 0, 0);
      acc[1][nt] = __builtin_amdgcn_mfma_f32_16x16x32_bf16(af[1][ks], wf, acc[1][nt], 0, 0, 0);
    }
#pragma unroll
  for (int mt = 0; mt < 2; ++mt)
#pragma unroll
    for (int nt = 0; nt < 8; ++nt)
#pragma unroll
      for (int i = 0; i < 4; ++i) {
        int row = base + mt * 16 + q * 4 + i;
        if (nt < 4) U[(size_t)row * 64 + nt * 16 + cl] = acc[mt][nt][i];
        else        P[(size_t)row * 64 + (nt - 4) * 16 + cl] = f2bf(acc[mt][nt][i]);
      }
}

// ---------------- fused KNN v3: two-pass streaming MFMA + 64-subset tau + exact rescan ----
// Block = 4 waves, 64 rows (one batch). B panel double-buffered in LDS (16KB), sq staged.
// Pass 1: running f32 mins over 64 subsets/row (subset = st*16+cl, 32 elems each).
//   tau = rank-31 (lex) of the 64 subset-mins — same statistic as validated R4-R8.
// Pass 2: recompute (bit-identical MFMA), collect d <= tau + 1.03125 (=2E+eps, E=0.5).
// Exact fp32 rescan + rank-count select (validated). Exhaustive fallback if >128 cands.
__global__ __launch_bounds__(256) void knn2_kernel(const unsigned short* __restrict__ xbf,
                                                   const float* __restrict__ x,
                                                   const float* __restrict__ sq,
                                                   int* __restrict__ idxout, int V) {
  __shared__ float sSq[2048];                              // 8KB (V==2048)
  __shared__ __align__(16) unsigned short sB[2][64 * 64];  // 16KB dbuf B panel
  __shared__ __align__(16) char sWS[4][5184];              // per-wave: sm/pool (4KB) + pool2 (1088B)
  __shared__ float sTau[4][16];
  __shared__ unsigned int sCnt[4][16];

  int t = threadIdx.x;
  int wv = t >> 6, lane = t & 63;
  int q = lane >> 4, cl = lane & 15;
  int Rblk = blockIdx.x * 64;
  int b = Rblk / V;
  size_t bbase = (size_t)b * V;
  const unsigned short* xbfb = xbf + bbase * FDIM;
  int Rw = Rblk + wv * 16;
  int v0w = Rw - b * V;
  int nch = V / 64;  // 32

  // stage sSq (whole batch)
  for (int o = t * 4; o < V; o += 1024)
    *reinterpret_cast<float4*>(&sSq[o]) = *reinterpret_cast<const float4*>(&sq[bbase + o]);

  // A-frags: 16 rows/wave, row index = cl, k = ks*32 + q*8
  s8v af[2];
  af[0] = *reinterpret_cast<const s8v*>(xbfb + (size_t)(v0w + cl) * FDIM + q * 8);
  af[1] = *reinterpret_cast<const s8v*>(xbfb + (size_t)(v0w + cl) * FDIM + 32 + q * 8);

  // chunk staging: thread t loads col (t>>2) of chunk, k = (t&3)*16 .. +16
  int scol = t >> 2, sk = (t & 3) * 16;
  s8v nx0, nx1;
  {
    const unsigned short* src = xbfb + (size_t)scol * FDIM + sk;
    nx0 = *reinterpret_cast<const s8v*>(src);
    nx1 = *reinterpret_cast<const s8v*>(src + 8);
    *reinterpret_cast<s8v*>(&sB[0][swzi(scol, sk, 64)]) = nx0;
    *reinterpret_cast<s8v*>(&sB[0][swzi(scol, sk + 8, 64)]) = nx1;
  }
  __syncthreads();

  const float PINF = __builtin_inff();
  float rmin[4][4];
#pragma unroll
  for (int st = 0; st < 4; ++st)
#pragma unroll
    for (int i = 0; i < 4; ++i) rmin[st][i] = PINF;

  // ---- pass 1: 64 subset mins per row (subset id = st*16+cl, 32 elems each) ----
  for (int cc = 0; cc < nch; ++cc) {
    if (cc + 1 < nch) {  // issue next-chunk loads early (T14)
      const unsigned short* src = xbfb + (size_t)((cc + 1) * 64 + scol) * FDIM + sk;
      nx0 = *reinterpret_cast<const s8v*>(src);
      nx1 = *reinterpret_cast<const s8v*>(src + 8);
    }
    int buf = cc & 1;
#pragma unroll
    for (int st = 0; st < 4; ++st) {
      s8v b0 = *reinterpret_cast<const s8v*>(&sB[buf][swzi(st * 16 + cl, q * 8, 64)]);
      s8v b1 = *reinterpret_cast<const s8v*>(&sB[buf][swzi(st * 16 + cl, 32 + q * 8, 64)]);
      f4v z = {0.f, 0.f, 0.f, 0.f};
      f4v a = __builtin_amdgcn_mfma_f32_16x16x32_bf16(af[0], b0, z, 0, 0, 0);
      a = __builtin_amdgcn_mfma_f32_16x16x32_bf16(af[1], b1, a, 0, 0, 0);
      float sqv = sSq[cc * 64 + st * 16 + cl];
#pragma unroll
      for (int i = 0; i < 4; ++i) {
        float d = fmaf(-2.f, a[i], sqv);
        rmin[st][i] = fminf(rmin[st][i], d);
      }
    }
    if (cc + 1 < nch) {  // write-late into other buffer
      *reinterpret_cast<s8v*>(&sB[buf ^ 1][swzi(scol, sk, 64)]) = nx0;
      *reinterpret_cast<s8v*>(&sB[buf ^ 1][swzi(scol, sk + 8, 64)]) = nx1;
    }
    __syncthreads();
  }

  // ---- tau per row: rank-31 (lex) of the 64 subset-mins (LDS rank-count, R8 method) ----
  float(*sm)[64] = reinterpret_cast<float(*)[64]>(&sWS[wv][0]);
#pragma unroll
  for (int st = 0; st < 4; ++st)
#pragma unroll
    for (int i = 0; i < 4; ++i) sm[q * 4 + i][st * 16 + cl] = rmin[st][i];
  lds_fence();
  for (int r = 0; r < 16; ++r) {
    float v = sm[r][lane];
    int c = 0;
#pragma unroll 8
    for (int j = 0; j < 64; ++j) {
      float vj = sm[r][j];
      c += (vj < v) || (vj == v && j < lane);
    }
    if (c == 30) sTau[wv][r] = v;  // exactly one lane (lex rank unique)
  }
  if (lane < 16) sCnt[wv][lane] = 0;
  lds_fence();
  float thr[4];
#pragma unroll
  for (int i = 0; i < 4; ++i) thr[i] = sTau[wv][q * 4 + i] + 1.03125f;

  // ---- pass 2: collect candidates (bit-identical MFMA recompute) ----
  unsigned short(*pool)[128] = reinterpret_cast<unsigned short(*)[128]>(&sWS[wv][0]);
  unsigned int* cnt = &sCnt[wv][0];
  {
    const unsigned short* src = xbfb + (size_t)scol * FDIM + sk;
    nx0 = *reinterpret_cast<const s8v*>(src);
    nx1 = *reinterpret_cast<const s8v*>(src + 8);
    *reinterpret_cast<s8v*>(&sB[0][swzi(scol, sk, 64)]) = nx0;
    *reinterpret_cast<s8v*>(&sB[0][swzi(scol, sk + 8, 64)]) = nx1;
  }
  __syncthreads();
  for (int cc = 0; cc < nch; ++cc) {
    if (cc + 1 < nch) {
      const unsigned short* src = xbfb + (size_t)((cc + 1) * 64 + scol) * FDIM + sk;
      nx0 = *reinterpret_cast<const s8v*>(src);
      nx1 = *reinterpret_cast<const s8v*>(src + 8);
    }
    int buf = cc & 1;
#pragma unroll
    for (int st = 0; st < 4; ++st) {
      s8v b0 = *reinterpret_cast<const s8v*>(&sB[buf][swzi(st * 16 + cl, q * 8, 64)]);
      s8v b1 = *reinterpret_cast<const s8v*>(&sB[buf][swzi(st * 16 + cl, 32 + q * 8, 64)]);
      f4v z = {0.f, 0.f, 0.f, 0.f};
      f4v a = __builtin_amdgcn_mfma_f32_16x16x32_bf16(af[0], b0, z, 0, 0, 0);
      a = __builtin_amdgcn_mfma_f32_16x16x32_bf16(af[1], b1, a, 0, 0, 0);
      int col = cc * 64 + st * 16 + cl;
      float sqv = sSq[col];
#pragma unroll
      for (int i = 0; i < 4; ++i) {
        float d = fmaf(-2.f, a[i], sqv);
        if (d <= thr[i]) {
          unsigned s = atomicAdd(&cnt[q * 4 + i], 1u);
          if (s < 128) pool[q * 4 + i][s] = (unsigned short)col;
        }
      }
    }
    if (cc + 1 < nch) {
      *reinterpret_cast<s8v*>(&sB[buf ^ 1][swzi(scol, sk, 64)]) = nx0;
      *reinterpret_cast<s8v*>(&sB[buf ^ 1][swzi(scol, sk + 8, 64)]) = nx1;
    }
    __syncthreads();
  }
  lds_fence();

  // ---- exact fp32 rescan + rank-count select, per row (wave-local) ----
  u64* pool2 = reinterpret_cast<u64*>(&sWS[wv][4096]);  // 136 u64
  int g8 = lane >> 3, sub = lane & 7;
  for (int r = 0; r < 16; ++r) {
    int cn = (int)cnt[r];
    int R = Rw + r;
    if (cn <= 128) {
      const float* xvp = x + (size_t)R * FDIM + sub * 8;
      float4 xa = *reinterpret_cast<const float4*>(xvp);
      float4 xb2 = *reinterpret_cast<const float4*>(xvp + 4);
      int rounds = (cn + 7) >> 3;
      for (int it = 0; it < rounds; ++it) {
        int c = it * 8 + g8;
        int w = pool[r][c < cn ? c : 0];
        const float* xwp = x + (bbase + (unsigned)w) * FDIM + sub * 8;
        float4 b0 = *reinterpret_cast<const float4*>(xwp);
        float4 b1 = *reinterpret_cast<const float4*>(xwp + 4);
        float dot = xa.x * b0.x;
        dot = fmaf(xa.y, b0.y, dot); dot = fmaf(xa.z, b0.z, dot);
        dot = fmaf(xa.w, b0.w, dot); dot = fmaf(xb2.x, b1.x, dot);
        dot = fmaf(xb2.y, b1.y, dot); dot = fmaf(xb2.z, b1.z, dot);
        dot = fmaf(xb2.w, b1.w, dot);
        dot += __shfl_xor(dot, 1);
        dot += __shfl_xor(dot, 2);
        dot += __shfl_xor(dot, 4);
        float dx = fmaf(-2.f, dot, sSq[w]);
        if (sub == 0 && c < cn) pool2[c] = ((u64)f2sort(dx) << 32) | (unsigned)w;
      }
      int nb = (cn + 7) & ~7;
      if (lane < nb - cn) pool2[cn + lane] = ~0ULL;
      lds_fence();
      u64 k1 = pool2[lane];
      u64 k2 = (64 + lane < nb) ? pool2[64 + lane] : ~0ULL;
      int rk1 = 0, rk2 = 0;
      for (int d0 = 0; d0 < nb; d0 += 8) {
#pragma unroll
        for (int u = 0; u < 8; ++u) {
          u64 v = pool2[d0 + u];
          rk1 += (v < k1);
          rk2 += (v < k2);
        }
      }
      if (lane < cn && rk1 >= 1 && rk1 <= KNN)
        idxout[(size_t)R * KNN + (rk1 - 1)] = (int)(unsigned)(k1 & 0xFFFFFFFFu);
      if (64 + lane < cn && rk2 >= 1 && rk2 <= KNN)
        idxout[(size_t)R * KNN + (rk2 - 1)] = (int)(unsigned)(k2 & 0xFFFFFFFFu);
      lds_fence();
    } else {
      // exhaustive exact fallback (field-validated R9; pathological clustering only)
      float* sXvf = reinterpret_cast<float*>(pool2);
      sXvf[lane] = x[(size_t)R * FDIM + lane];
      lds_fence();
      unsigned int sve[32];
#pragma unroll 1
      for (int rr = 0; rr < 32; ++rr) {
        int w = rr * 64 + lane;
        const float* xw = x + (bbase + (unsigned)w) * FDIM;
        float dot = 0.f;
        for (int f = 0; f < FDIM; ++f) dot = fmaf(sXvf[f], xw[f], dot);
        sve[rr] = f2sort(fmaf(-2.f, dot, sSq[w]));
      }
      unsigned removed = 0;
      for (int it = 0; it < KNN + 1; ++it) {
        u64 m2 = ~0ULL;
#pragma unroll
        for (int rr = 0; rr < 32; ++rr) {
          u64 key = ((u64)sve[rr] << 32) | (unsigned)(rr * 64 + lane);
          bool alive = ((removed >> rr) & 1u) == 0u;
          if (alive && key < m2) m2 = key;
        }
        u64 gk = m2;
#pragma unroll
        for (int off = 32; off; off >>= 1) {
          u64 o = __shfl_xor(gk, off);
          gk = (o < gk) ? o : gk;
        }
        if (it > 0 && lane == 0)
          idxout[(size_t)R * KNN + (it - 1)] = (int)(unsigned)(gk & 0xFFFFFFFFu);
#pragma unroll
        for (int rr = 0; rr < 32; ++rr) {
          u64 key = ((u64)sve[rr] << 32) | (unsigned)(rr * 64 + lane);
          if (key == gk) removed |= (1u << rr);
        }
      }
      lds_fence();
    }
  }
}

// ---------------- fused layers 2,3 + max aggregation ----------------
__global__ __launch_bounds__(256) void mlp_kernel(const float* __restrict__ U,
                                                  const unsigned short* __restrict__ P,
                                                  const int* __restrict__ idx,
                                                  const float* __restrict__ W2,
                                                  const float* __restrict__ b2,
                                                  const float* __restrict__ W3,
                                                  const float* __restrict__ b3,
                                                  float* __restrict__ out, int V) {
  __shared__ __align__(16) unsigned short sW2T[HDIM * HDIM];
  __shared__ __align__(16) unsigned short sW3T[HDIM * HDIM];
  __shared__ __align__(16) unsigned short sScr[4][2048];
  int t = threadIdx.x;
  for (int e = t; e < HDIM * HDIM; e += 256) {
    int i = e >> 6, j = e & 63;
    sW2T[swzi(j, i, 64)] = f2bf(W2[e]);
    int s = (i & 15) * 4 + (i >> 4);
    sW3T[swzi(j, s, 64)] = f2bf(W3[e]);
  }
  __syncthreads();

  int wv = t >> 6, lane = t & 63;
  int q = lane >> 4, cl = lane & 15;
  int g = lane >> 3, sub = lane & 7;
  unsigned short* scr = &sScr[wv][0];
  float bias2[4], bias3[4];
#pragma unroll
  for (int nt = 0; nt < 4; ++nt) {
    bias2[nt] = b2[nt * 16 + cl];
    bias3[nt] = b3[nt * 16 + cl];
  }

  for (int vi = 0; vi < 4; ++vi) {
    int v = blockIdx.x * 16 + wv * 4 + vi;
    int b = v / V;
    size_t bbase = (size_t)b * V;
    int myidx = (lane < KNN) ? idx[(size_t)v * KNN + lane] : 0;
    const float* up = U + (size_t)v * 64 + sub * 8;
    float4 u0 = *reinterpret_cast<const float4*>(up);
    float4 u1 = *reinterpret_cast<const float4*>(up + 4);
    float uu[8] = {u0.x, u0.y, u0.z, u0.w, u1.x, u1.y, u1.z, u1.w};

#pragma unroll
    for (int it = 0; it < 4; ++it) {
      int r = it * 8 + g;
      int kk = (r < KNN) ? r : (KNN - 1);
      int nb = __shfl(myidx, kk);
      const unsigned short* pp = P + (bbase + (unsigned int)nb) * 64 + sub * 8;
      s8v p8 = *reinterpret_cast<const s8v*>(pp);
      s8v hv;
#pragma unroll
      for (int j = 0; j < 8; ++j) {
        float f = uu[j] - bf2f((unsigned short)p8[j]);
        hv[j] = (short)f2bf(fmaxf(f, 0.0f));
      }
      *reinterpret_cast<s8v*>(&scr[swzi(r, sub * 8, 64)]) = hv;
    }
    lds_fence();

    s8v af2[2][2];
#pragma unroll
    for (int mt = 0; mt < 2; ++mt)
#pragma unroll
      for (int ks = 0; ks < 2; ++ks)
        af2[mt][ks] = *reinterpret_cast<const s8v*>(&scr[swzi(mt * 16 + cl, ks * 32 + q * 8, 64)]);
    f4v acc2[2][4];
#pragma unroll
    for (int mt = 0; mt < 2; ++mt)
#pragma unroll
      for (int nt = 0; nt < 4; ++nt) {
        f4v a0 = {bias2[nt], bias2[nt], bias2[nt], bias2[nt]};
        acc2[mt][nt] = a0;
      }
#pragma unroll
    for (int ks = 0; ks < 2; ++ks)
#pragma unroll
      for (int nt = 0; nt < 4; ++nt) {
        s8v wf = *reinterpret_cast<const s8v*>(&sW2T[swzi(nt * 16 + cl, ks * 32 + q * 8, 64)]);
        acc2[0][nt] = __builtin_amdgcn_mfma_f32_16x16x32_bf16(af2[0][ks], wf, acc2[0][nt], 0, 0, 0);
        acc2[1][nt] = __builtin_amdgcn_mfma_f32_16x16x32_bf16(af2[1][ks], wf, acc2[1][nt], 0, 0, 0);
      }
    lds_fence();
#pragma unroll
    for (int mt = 0; mt < 2; ++mt)
#pragma unroll
      for (int i = 0; i < 4; ++i) {
        int m = mt * 16 + q * 4 + i;
        u64 pk = 0;
#pragma unroll
        for (int nt = 0; nt < 4; ++nt) {
          u64 hb = f2bf(fmaxf(acc2[mt][nt][i], 0.0f));
          pk |= hb << (16 * nt);
        }
        *reinterpret_cast<u64*>(&scr[swzi(m, cl * 4, 64)]) = pk;
      }
    lds_fence();

    s8v af3[2][2];
#pragma unroll
    for (int mt = 0; mt < 2; ++mt)
#pragma unroll
      for (int ks = 0; ks < 2; ++ks)
        af3[mt][ks] = *reinterpret_cast<const s8v*>(&scr[swzi(mt * 16 + cl, ks * 32 + q * 8, 64)]);
    f4v acc3[2][4];
#pragma unroll
    for (int mt = 0; mt < 2; ++mt)
#pragma unroll
      for (int nt = 0; nt < 4; ++nt) {
        f4v a0 = {bias3[nt], bias3[nt], bias3[nt], bias3[nt]};
        acc3[mt][nt] = a0;
      }
#pragma unroll
    for (int ks = 0; ks < 2; ++ks)
#pragma unroll
      for (int nt = 0; nt < 4; ++nt) {
        s8v wf = *reinterpret_cast<const s8v*>(&sW3T[swzi(nt * 16 + cl, ks * 32 + q * 8, 64)]);
        acc3[0][nt] = __builtin_amdgcn_mfma_f32_16x16x32_bf16(af3[0][ks], wf, acc3[0][nt], 0, 0, 0);
        acc3[1][nt] = __builtin_amdgcn_mfma_f32_16x16x32_bf16(af3[1][ks], wf, acc3[1][nt], 0, 0, 0);
      }

    float m[4] = {0.0f, 0.0f, 0.0f, 0.0f};
#pragma unroll
    for (int nt = 0; nt < 4; ++nt)
#pragma unroll
      for (int mt = 0; mt < 2; ++mt)
#pragma unroll
        for (int i = 0; i < 4; ++i) m[nt] = fmaxf(m[nt], acc3[mt][nt][i]);
#pragma unroll
    for (int nt = 0; nt < 4; ++nt) {
      m[nt] = fmaxf(m[nt], __shfl_xor(m[nt], 16));
      m[nt] = fmaxf(m[nt], __shfl_xor(m[nt], 32));
    }
    float outv = (q == 0) ? m[0] : (q == 1) ? m[1] : (q == 2) ? m[2] : m[3];
    out[(size_t)v * HDIM + lane] = outv;
  }
}

extern "C" void kernel_launch(void* const* d_in, const int* in_sizes, int n_in,
                              void* d_out, int out_size, void* d_ws, size_t ws_size,
                              hipStream_t stream) {
  const float* x  = (const float*)d_in[0];
  const float* W1 = (const float*)d_in[2];
  const float* b1 = (const float*)d_in[3];
  const float* W2 = (const float*)d_in[4];
  const float* b2 = (const float*)d_in[5];
  const float* W3 = (const float*)d_in[6];
  const float* b3 = (const float*)d_in[7];
  float* out = (float*)d_out;
  int N = in_sizes[0] / FDIM;      // 32768
  int B = in_sizes[1] - 1;         // 16
  int V = N / B;                   // 2048

  char* ws = (char*)d_ws;
  float* sqbuf = (float*)ws;
  size_t off = (size_t)N * sizeof(float);
  int* idxbuf = (int*)(ws + off);
  off += (size_t)N * KNN * sizeof(int);
  off = (off + 255) & ~(size_t)255;
  float* Ubuf = (float*)(ws + off);
  off += (size_t)N * 64 * sizeof(float);
  unsigned short* Pbuf = (unsigned short*)(ws + off);
  off += (size_t)N * 64 * sizeof(unsigned short);
  off = (off + 255) & ~(size_t)255;
  unsigned short* xbfbuf = (unsigned short*)(ws + off);

  prep_kernel<<<N / 32, 256, 0, stream>>>(x, xbfbuf, sqbuf);
  uP_kernel<<<N / 128, 256, 0, stream>>>(x, W1, b1, Ubuf, Pbuf);
  knn2_kernel<<<N / 64, 256, 0, stream>>>(xbfbuf, x, sqbuf, idxbuf, V);
  mlp_kernel<<<N / 16, 256, 0, stream>>>(Ubuf, Pbuf, idxbuf, W2, b2, W3, b3, out, V);
}

// Round 11
// 195.191 us; speedup vs baseline: 9.2530x; 1.2024x over previous
//
#include <hip/hip_runtime.h>

#define KNN 30
#define FDIM 64
#define HDIM 64

typedef short s8v __attribute__((ext_vector_type(8)));   // 8 bf16 bit-patterns (4 VGPR)
typedef unsigned short u16x8 __attribute__((ext_vector_type(8)));
typedef float f4v __attribute__((ext_vector_type(4)));   // MFMA accumulator
typedef unsigned long long u64;

// round-to-nearest-even f32 -> bf16 bits
static __device__ __forceinline__ unsigned short f2bf(float f) {
  unsigned int u = __builtin_bit_cast(unsigned int, f);
  u += 0x7fffu + ((u >> 16) & 1u);
  return (unsigned short)(u >> 16);
}
static __device__ __forceinline__ float bf2f(unsigned short h) {
  unsigned int u = ((unsigned int)h) << 16;
  return __builtin_bit_cast(float, u);
}

// f32 bits -> order-preserving u32 (asc float order == asc uint order)
static __device__ __forceinline__ unsigned int f2sort(float f) {
  unsigned int u = __builtin_bit_cast(unsigned int, f);
  unsigned int m = (unsigned int)(((int)u) >> 31) | 0x80000000u;
  return u ^ m;
}

// XOR swizzle (ushort-index space): byte ^= (row&7)<<4  <=>  idx ^= (row&7)<<3
static __device__ __forceinline__ int swzi(int row, int col, int roww) {
  return (row * roww + col) ^ ((row & 7) << 3);
}

static __device__ __forceinline__ void lds_fence() {
  asm volatile("s_waitcnt lgkmcnt(0)" ::: "memory");
  __builtin_amdgcn_sched_barrier(0);
}

static __device__ __forceinline__ s8v pack8(float4 a, float4 b) {
  s8v v;
  v[0] = (short)f2bf(a.x); v[1] = (short)f2bf(a.y);
  v[2] = (short)f2bf(a.z); v[3] = (short)f2bf(a.w);
  v[4] = (short)f2bf(b.x); v[5] = (short)f2bf(b.y);
  v[6] = (short)f2bf(b.z); v[7] = (short)f2bf(b.w);
  return v;
}

// ---------------- prep: xbf = bf16(x) and sq = |x|^2 (exact f32) ----------------
__global__ __launch_bounds__(256) void prep_kernel(const float* __restrict__ x,
                                                   unsigned short* __restrict__ xbf,
                                                   float* __restrict__ sq) {
  int t = threadIdx.x;
  int r = blockIdx.x * 32 + (t >> 3);
  int sub = t & 7;
  const float* p = x + (size_t)r * FDIM + sub * 8;
  float4 a = *reinterpret_cast<const float4*>(p);
  float4 b = *reinterpret_cast<const float4*>(p + 4);
  *reinterpret_cast<s8v*>(xbf + (size_t)r * FDIM + sub * 8) = pack8(a, b);
  float s = a.x * a.x;
  s = fmaf(a.y, a.y, s); s = fmaf(a.z, a.z, s); s = fmaf(a.w, a.w, s);
  s = fmaf(b.x, b.x, s); s = fmaf(b.y, b.y, s); s = fmaf(b.z, b.z, s);
  s = fmaf(b.w, b.w, s);
  s += __shfl_xor(s, 1);
  s += __shfl_xor(s, 2);
  s += __shfl_xor(s, 4);
  if (sub == 0) sq[r] = s;
}

// ---------------- U/P precompute (layer-1 algebraic elimination) ----------------
__global__ __launch_bounds__(256) void uP_kernel(const float* __restrict__ x,
                                                 const float* __restrict__ W1,
                                                 const float* __restrict__ b1,
                                                 float* __restrict__ U,
                                                 unsigned short* __restrict__ P) {
  __shared__ __align__(16) unsigned short sWT[128 * 64];
  int t = threadIdx.x;
  for (int e = t; e < 64 * 64; e += 256) {
    int f = e >> 6, h = e & 63;
    float wa = W1[f * 64 + h];
    float wb = W1[(64 + f) * 64 + h];
    sWT[swzi(h, f, 64)] = f2bf(wa + wb);
    sWT[swzi(64 + h, f, 64)] = f2bf(wb);
  }
  __syncthreads();
  int wv = t >> 6, lane = t & 63;
  int q = lane >> 4, cl = lane & 15;
  int base = blockIdx.x * 128 + wv * 32;

  s8v af[2][2];
#pragma unroll
  for (int mt = 0; mt < 2; ++mt)
#pragma unroll
    for (int ks = 0; ks < 2; ++ks) {
      const float* px = x + (size_t)(base + mt * 16 + cl) * FDIM + ks * 32 + q * 8;
      float4 a = *reinterpret_cast<const float4*>(px);
      float4 b = *reinterpret_cast<const float4*>(px + 4);
      af[mt][ks] = pack8(a, b);
    }
  f4v acc[2][8];
#pragma unroll
  for (int nt = 0; nt < 8; ++nt) {
    float bb = (nt < 4) ? b1[nt * 16 + cl] : 0.0f;
    f4v a0 = {bb, bb, bb, bb};
    acc[0][nt] = a0;
    acc[1][nt] = a0;
  }
#pragma unroll
  for (int ks = 0; ks < 2; ++ks)
#pragma unroll
    for (int nt = 0; nt < 8; ++nt) {
      s8v wf = *reinterpret_cast<const s8v*>(&sWT[swzi(nt * 16 + cl, ks * 32 + q * 8, 64)]);
      acc[0][nt] = __builtin_amdgcn_mfma_f32_16x16x32_bf16(af[0][ks], wf, acc[0][nt], 0, 0, 0);
      acc[1][nt] = __builtin_amdgcn_mfma_f32_16x16x32_bf16(af[1][ks], wf, acc[1][nt], 0, 0, 0);
    }
#pragma unroll
  for (int mt = 0; mt < 2; ++mt)
#pragma unroll
    for (int nt = 0; nt < 8; ++nt)
#pragma unroll
      for (int i = 0; i < 4; ++i) {
        int row = base + mt * 16 + q * 4 + i;
        if (nt < 4) U[(size_t)row * 64 + nt * 16 + cl] = acc[mt][nt][i];
        else        P[(size_t)row * 64 + (nt - 4) * 16 + cl] = f2bf(acc[mt][nt][i]);
      }
}

// ---------------- dist16 v3: register-direct bf16 MFMA Gram -> u16 keys (R6-validated) ----
__global__ __launch_bounds__(256) void dist16_kernel(const unsigned short* __restrict__ xbf,
                                                     const float* __restrict__ sq,
                                                     unsigned short* __restrict__ D16,
                                                     int R0, int V) {
  __shared__ __align__(16) unsigned short sK[128 * 128];  // 32KB key tile
  int t = threadIdx.x;
  int R = R0 + blockIdx.y * 128;
  int b = R / V;
  int w0 = blockIdx.x * 128;
  size_t bbase = (size_t)b * V;
  int wv = t >> 6, lane = t & 63;
  int q = lane >> 4, cl = lane & 15;
  int mq = wv >> 1, nq = wv & 1;  // 64x64 quadrant per wave

  s8v af[4][2], bfr[4][2];
#pragma unroll
  for (int mt = 0; mt < 4; ++mt)
#pragma unroll
    for (int ks = 0; ks < 2; ++ks) {
      af[mt][ks] = *reinterpret_cast<const s8v*>(
          xbf + (size_t)(R + mq * 64 + mt * 16 + cl) * FDIM + ks * 32 + q * 8);
      bfr[mt][ks] = *reinterpret_cast<const s8v*>(
          xbf + (bbase + (size_t)(w0 + nq * 64 + mt * 16 + cl)) * FDIM + ks * 32 + q * 8);
    }
  f4v acc[4][4];
#pragma unroll
  for (int mt = 0; mt < 4; ++mt)
#pragma unroll
    for (int nt = 0; nt < 4; ++nt) {
      f4v z = {0.0f, 0.0f, 0.0f, 0.0f};
      acc[mt][nt] = z;
    }
#pragma unroll
  for (int ks = 0; ks < 2; ++ks)
#pragma unroll
    for (int mt = 0; mt < 4; ++mt)
#pragma unroll
      for (int nt = 0; nt < 4; ++nt)
        acc[mt][nt] = __builtin_amdgcn_mfma_f32_16x16x32_bf16(af[mt][ks], bfr[nt][ks], acc[mt][nt], 0, 0, 0);
  float sql[4];
#pragma unroll
  for (int nt = 0; nt < 4; ++nt) sql[nt] = sq[bbase + w0 + nq * 64 + nt * 16 + cl];

  // keys -> LDS (row-swizzled)
#pragma unroll
  for (int mt = 0; mt < 4; ++mt)
#pragma unroll
    for (int nt = 0; nt < 4; ++nt)
#pragma unroll
      for (int i = 0; i < 4; ++i) {
        int rl = mq * 64 + mt * 16 + q * 4 + i;
        int cll = nq * 64 + nt * 16 + cl;
        float dk = fmaf(-128.0f, acc[mt][nt][i], fmaf(64.0f, sql[nt], 16384.0f));
        int ki = (int)(dk + 0.5f);
        ki = ki < 0 ? 0 : (ki > 65535 ? 65535 : ki);
        sK[rl * 128 + (cll ^ ((rl & 7) << 3))] = (unsigned short)ki;
      }
  __syncthreads();

  // coalesced store: 8-lane group writes one row's 256B contiguously
  {
    int sub = t & 7, rbase = t >> 3;
#pragma unroll
    for (int i = 0; i < 4; ++i) {
      int rr = i * 32 + rbase;
      int sw = (rr & 7) << 3;
      int c1 = (sub * 16) ^ sw;
      int c2 = (sub * 16 + 8) ^ sw;
      s8v k0 = *reinterpret_cast<const s8v*>(&sK[rr * 128 + c1]);
      s8v k1 = *reinterpret_cast<const s8v*>(&sK[rr * 128 + c2]);
      size_t gb = (size_t)(blockIdx.y * 128 + rr) * (size_t)V + w0 + sub * 16;
      *reinterpret_cast<s8v*>(D16 + gb) = k0;
      *reinterpret_cast<s8v*>(D16 + gb + 8) = k1;
    }
  }
}

// ---------------- topk16 v2 (R6-validated, 84us): packed-min tau + prefix compaction ----
// Margin: |d_bf16 - d_fp32| <= E (=0.5, ~10 sigma) -> 128E+2 = 66 key units.
// tau = rank-30 of the 64 per-lane key minima (upper bound on true rank-31 key).
__global__ __launch_bounds__(256) void topk16_kernel(const unsigned short* __restrict__ D16,
                                                     const float* __restrict__ x,
                                                     const float* __restrict__ sq,
                                                     int* __restrict__ idxout,
                                                     int R0, int nrows, int V) {
  __shared__ unsigned int pool[4][128];
  __shared__ u64 pool2[4][128];
  __shared__ float sXv[4][64];
  int wave = threadIdx.x >> 6, lane = threadIdx.x & 63;
  int rowL = blockIdx.x * 4 + wave;
  if (rowL >= nrows) return;
  int R = R0 + rowL;
  int b = R / V;
  size_t bbase = (size_t)b * V;
  const unsigned short* row16 = D16 + (size_t)rowL * (size_t)V;

  // 32 keys/lane as 4 ushort8 registers; value (s,j) sits at col s*512 + lane*8 + j
  u16x8 r0 = *reinterpret_cast<const u16x8*>(row16 + 0 * 512 + lane * 8);
  u16x8 r1 = *reinterpret_cast<const u16x8*>(row16 + 1 * 512 + lane * 8);
  u16x8 r2 = *reinterpret_cast<const u16x8*>(row16 + 2 * 512 + lane * 8);
  u16x8 r3 = *reinterpret_cast<const u16x8*>(row16 + 3 * 512 + lane * 8);

  // per-lane min via packed u16 mins
  u16x8 m01 = __builtin_elementwise_min(r0, r1);
  u16x8 m23 = __builtin_elementwise_min(r2, r3);
  u16x8 m = __builtin_elementwise_min(m01, m23);
  unsigned int mn = m[0];
#pragma unroll
  for (int j = 1; j < 8; ++j) mn = min(mn, (unsigned int)m[j]);

  // bitonic-64 of lane minima -> tau (rank 30) bounds true rank-31 key from above
  unsigned int srt = mn;
#pragma unroll
  for (int k = 2; k <= 64; k <<= 1) {
#pragma unroll
    for (int j = k >> 1; j > 0; j >>= 1) {
      unsigned int o = __shfl_xor(srt, j);
      bool keep_min = ((lane & k) == 0) == ((lane & j) == 0);
      bool less = srt < o;
      srt = (keep_min == less) ? srt : o;
    }
  }
  unsigned int tauk = __shfl(srt, 30) + 66;

  // pass 1: per-lane candidate count
  int cnt = 0;
#pragma unroll
  for (int j = 0; j < 8; ++j) {
    cnt += (r0[j] <= tauk);
    cnt += (r1[j] <= tauk);
    cnt += (r2[j] <= tauk);
    cnt += (r3[j] <= tauk);
  }
  // inclusive prefix sum over 64 lanes
  int pre = cnt;
#pragma unroll
  for (int off = 1; off < 64; off <<= 1) {
    int o = __shfl_up(pre, off);
    if (lane >= off) pre += o;
  }
  int total = __shfl(pre, 63);
  int mybase = pre - cnt;

  if (total <= 128) {
    // pass 2: scatter candidates into pool at prefix offsets
    int slot = mybase;
#pragma unroll
    for (int j = 0; j < 8; ++j) {
      if (r0[j] <= tauk) { pool[wave][slot] = ((unsigned int)r0[j] << 16) | (unsigned int)(0 * 512 + lane * 8 + j); slot++; }
      if (r1[j] <= tauk) { pool[wave][slot] = ((unsigned int)r1[j] << 16) | (unsigned int)(1 * 512 + lane * 8 + j); slot++; }
      if (r2[j] <= tauk) { pool[wave][slot] = ((unsigned int)r2[j] << 16) | (unsigned int)(2 * 512 + lane * 8 + j); slot++; }
      if (r3[j] <= tauk) { pool[wave][slot] = ((unsigned int)r3[j] << 16) | (unsigned int)(3 * 512 + lane * 8 + j); slot++; }
    }
    lds_fence();
    int base = total;
    // exact fp32 rescan: 8-lane groups, group g handles candidates it*8+g
    int g = lane >> 3, sub = lane & 7;
    const float* xvp = x + (size_t)R * FDIM + sub * 8;
    float4 xv0 = *reinterpret_cast<const float4*>(xvp);
    float4 xv1 = *reinterpret_cast<const float4*>(xvp + 4);
    float xv[8] = {xv0.x, xv0.y, xv0.z, xv0.w, xv1.x, xv1.y, xv1.z, xv1.w};
    int rounds = (base + 7) >> 3;
    for (int it = 0; it < rounds; ++it) {
      int c = it * 8 + g;
      unsigned int pk = pool[wave][c < base ? c : 0];
      int w = (int)(pk & 0xFFFFu);
      const float* xwp = x + (bbase + (unsigned int)w) * FDIM + sub * 8;
      float4 b0 = *reinterpret_cast<const float4*>(xwp);
      float4 b1 = *reinterpret_cast<const float4*>(xwp + 4);
      float dot = xv[0] * b0.x;
      dot = fmaf(xv[1], b0.y, dot); dot = fmaf(xv[2], b0.z, dot);
      dot = fmaf(xv[3], b0.w, dot); dot = fmaf(xv[4], b1.x, dot);
      dot = fmaf(xv[5], b1.y, dot); dot = fmaf(xv[6], b1.z, dot);
      dot = fmaf(xv[7], b1.w, dot);
      dot += __shfl_xor(dot, 1);
      dot += __shfl_xor(dot, 2);
      dot += __shfl_xor(dot, 4);
      float dx = fmaf(-2.0f, dot, sq[bbase + (unsigned int)w]);
      if (sub == 0 && c < base)
        pool2[wave][c] = ((u64)f2sort(dx) << 32) | (unsigned int)w;
    }
    lds_fence();
    u64 keyA = (lane < base) ? pool2[wave][lane] : ~0ULL;
    if (base <= 64) {
#pragma unroll
      for (int k = 2; k <= 64; k <<= 1) {
#pragma unroll
        for (int j = k >> 1; j > 0; j >>= 1) {
          u64 o = __shfl_xor(keyA, j);
          bool keep_min = ((lane & k) == 0) == ((lane & j) == 0);
          bool less = keyA < o;
          keyA = (keep_min == less) ? keyA : o;
        }
      }
      if (lane >= 1 && lane <= KNN)
        idxout[(size_t)R * KNN + (lane - 1)] = (int)(unsigned int)(keyA & 0xFFFFFFFFu);
    } else {
      u64 keyB = (64 + lane < base) ? pool2[wave][64 + lane] : ~0ULL;
#pragma unroll
      for (int k = 2; k <= 64; k <<= 1) {
#pragma unroll
        for (int j = k >> 1; j > 0; j >>= 1) {
          u64 oA = __shfl_xor(keyA, j);
          bool keep_min = ((lane & k) == 0) == ((lane & j) == 0);
          keyA = (keep_min == (keyA < oA)) ? keyA : oA;
          u64 oB = __shfl_xor(keyB, j);
          keyB = (keep_min == (keyB < oB)) ? keyB : oB;
        }
      }
      // merge: A asc + reverse(B asc) -> elementwise min is bitonic & holds smallest 64
      u64 keyBr = __shfl(keyB, 63 - lane);
      u64 mnk = keyA < keyBr ? keyA : keyBr;
#pragma unroll
      for (int j = 32; j > 0; j >>= 1) {
        u64 o = __shfl_xor(mnk, j);
        bool keep_min = (lane & j) == 0;
        mnk = (keep_min == (mnk < o)) ? mnk : o;
      }
      if (lane >= 1 && lane <= KNN)
        idxout[(size_t)R * KNN + (lane - 1)] = (int)(unsigned int)(mnk & 0xFFFFFFFFu);
    }
  } else {
    // exhaustive exact fallback (pathological clustering only): full row in fp32
    sXv[wave][lane] = x[(size_t)R * FDIM + lane];
    lds_fence();
    unsigned int sve[32];
#pragma unroll 1
    for (int s = 0; s < 4; ++s)
#pragma unroll 1
      for (int j = 0; j < 8; ++j) {
        int w = s * 512 + lane * 8 + j;
        const float* xw = x + (bbase + (unsigned int)w) * FDIM;
        float dot = 0.0f;
        for (int f = 0; f < 64; ++f) dot = fmaf(sXv[wave][f], xw[f], dot);
        sve[s * 8 + j] = f2sort(fmaf(-2.0f, dot, sq[bbase + (unsigned int)w]));
      }
    unsigned int removed = 0;
    for (int it = 0; it < KNN + 1; ++it) {
      u64 m2 = ~0ULL;
#pragma unroll
      for (int r = 0; r < 32; ++r) {
        u64 key = ((u64)sve[r] << 32) | (unsigned int)((r >> 3) * 512 + lane * 8 + (r & 7));
        bool alive = ((removed >> r) & 1u) == 0u;
        if (alive && key < m2) m2 = key;
      }
      u64 gk = m2;
#pragma unroll
      for (int off = 32; off; off >>= 1) {
        u64 o = __shfl_xor(gk, off);
        gk = (o < gk) ? o : gk;
      }
      if (it > 0 && lane == 0) idxout[(size_t)R * KNN + (it - 1)] = (int)(unsigned int)(gk & 0xFFFFFFFFu);
#pragma unroll
      for (int r = 0; r < 32; ++r) {
        u64 key = ((u64)sve[r] << 32) | (unsigned int)((r >> 3) * 512 + lane * 8 + (r & 7));
        if (key == gk) removed |= (1u << r);
      }
    }
  }
}

// ---------------- fused layers 2,3 + max aggregation (v2: 1-deep gather prefetch) ----
// Per-vertex chain was idx->shfl->P-gather->H1->MFMA with gather latency exposed
// (sched_barrier fences block compiler hoisting). Pipeline: issue idx[v+1] at top of
// iter v; issue U/P[v+1] after the L2 MFMA block; rotate named registers (rule #20).
__global__ __launch_bounds__(256) void mlp_kernel(const float* __restrict__ U,
                                                  const unsigned short* __restrict__ P,
                                                  const int* __restrict__ idx,
                                                  const float* __restrict__ W2,
                                                  const float* __restrict__ b2,
                                                  const float* __restrict__ W3,
                                                  const float* __restrict__ b3,
                                                  float* __restrict__ out, int V) {
  __shared__ __align__(16) unsigned short sW2T[HDIM * HDIM];
  __shared__ __align__(16) unsigned short sW3T[HDIM * HDIM];
  __shared__ __align__(16) unsigned short sScr[4][2048];
  int t = threadIdx.x;
  for (int e = t; e < HDIM * HDIM; e += 256) {
    int i = e >> 6, j = e & 63;
    sW2T[swzi(j, i, 64)] = f2bf(W2[e]);
    int s = (i & 15) * 4 + (i >> 4);
    sW3T[swzi(j, s, 64)] = f2bf(W3[e]);
  }
  __syncthreads();

  int wv = t >> 6, lane = t & 63;
  int q = lane >> 4, cl = lane & 15;
  int g = lane >> 3, sub = lane & 7;
  unsigned short* scr = &sScr[wv][0];
  float bias2[4], bias3[4];
#pragma unroll
  for (int nt = 0; nt < 4; ++nt) {
    bias2[nt] = b2[nt * 16 + cl];
    bias3[nt] = b3[nt * 16 + cl];
  }

  int vbase = blockIdx.x * 16 + wv * 4;
  int b = vbase / V;  // 4 consecutive vertices never straddle a batch (V mult of 4)
  size_t bbase = (size_t)b * V;

  // gather row assignment: iteration it covers row r = it*8 + g; lane chunk sub*8
  int kk0 = (0 * 8 + g < KNN) ? 0 * 8 + g : KNN - 1;
  int kk1 = (1 * 8 + g < KNN) ? 1 * 8 + g : KNN - 1;
  int kk2 = (2 * 8 + g < KNN) ? 2 * 8 + g : KNN - 1;
  int kk3 = (3 * 8 + g < KNN) ? 3 * 8 + g : KNN - 1;

  // ---- prologue: load vertex 0 state ----
  int idxC = (lane < KNN) ? idx[(size_t)vbase * KNN + lane] : 0;
  const float* upC = U + (size_t)vbase * 64 + sub * 8;
  float4 uC0 = *reinterpret_cast<const float4*>(upC);
  float4 uC1 = *reinterpret_cast<const float4*>(upC + 4);
  s8v pC0, pC1, pC2, pC3;
  {
    int nb0 = __shfl(idxC, kk0), nb1 = __shfl(idxC, kk1);
    int nb2 = __shfl(idxC, kk2), nb3 = __shfl(idxC, kk3);
    pC0 = *reinterpret_cast<const s8v*>(P + (bbase + (unsigned)nb0) * 64 + sub * 8);
    pC1 = *reinterpret_cast<const s8v*>(P + (bbase + (unsigned)nb1) * 64 + sub * 8);
    pC2 = *reinterpret_cast<const s8v*>(P + (bbase + (unsigned)nb2) * 64 + sub * 8);
    pC3 = *reinterpret_cast<const s8v*>(P + (bbase + (unsigned)nb3) * 64 + sub * 8);
  }

  for (int vi = 0; vi < 4; ++vi) {
    int v = vbase + vi;
    // issue next vertex's idx load first (longest dependency chain)
    int idxN = 0;
    if (vi < 3) idxN = (lane < KNN) ? idx[(size_t)(v + 1) * KNN + lane] : 0;

    // ---- H1 build from prefetched registers ----
    float uu[8] = {uC0.x, uC0.y, uC0.z, uC0.w, uC1.x, uC1.y, uC1.z, uC1.w};
    {
      s8v hv;
#pragma unroll
      for (int j = 0; j < 8; ++j) {
        float f = uu[j] - bf2f((unsigned short)pC0[j]);
        hv[j] = (short)f2bf(fmaxf(f, 0.0f));
      }
      *reinterpret_cast<s8v*>(&scr[swzi(0 * 8 + g, sub * 8, 64)]) = hv;
#pragma unroll
      for (int j = 0; j < 8; ++j) {
        float f = uu[j] - bf2f((unsigned short)pC1[j]);
        hv[j] = (short)f2bf(fmaxf(f, 0.0f));
      }
      *reinterpret_cast<s8v*>(&scr[swzi(1 * 8 + g, sub * 8, 64)]) = hv;
#pragma unroll
      for (int j = 0; j < 8; ++j) {
        float f = uu[j] - bf2f((unsigned short)pC2[j]);
        hv[j] = (short)f2bf(fmaxf(f, 0.0f));
      }
      *reinterpret_cast<s8v*>(&scr[swzi(2 * 8 + g, sub * 8, 64)]) = hv;
#pragma unroll
      for (int j = 0; j < 8; ++j) {
        float f = uu[j] - bf2f((unsigned short)pC3[j]);
        hv[j] = (short)f2bf(fmaxf(f, 0.0f));
      }
      *reinterpret_cast<s8v*>(&scr[swzi(3 * 8 + g, sub * 8, 64)]) = hv;
    }
    lds_fence();

    // ---- layer 2 ----
    s8v af2[2][2];
#pragma unroll
    for (int mt = 0; mt < 2; ++mt)
#pragma unroll
      for (int ks = 0; ks < 2; ++ks)
        af2[mt][ks] = *reinterpret_cast<const s8v*>(&scr[swzi(mt * 16 + cl, ks * 32 + q * 8, 64)]);
    f4v acc2[2][4];
#pragma unroll
    for (int mt = 0; mt < 2; ++mt)
#pragma unroll
      for (int nt = 0; nt < 4; ++nt) {
        f4v a0 = {bias2[nt], bias2[nt], bias2[nt], bias2[nt]};
        acc2[mt][nt] = a0;
      }
#pragma unroll
    for (int ks = 0; ks < 2; ++ks)
#pragma unroll
      for (int nt = 0; nt < 4; ++nt) {
        s8v wf = *reinterpret_cast<const s8v*>(&sW2T[swzi(nt * 16 + cl, ks * 32 + q * 8, 64)]);
        acc2[0][nt] = __builtin_amdgcn_mfma_f32_16x16x32_bf16(af2[0][ks], wf, acc2[0][nt], 0, 0, 0);
        acc2[1][nt] = __builtin_amdgcn_mfma_f32_16x16x32_bf16(af2[1][ks], wf, acc2[1][nt], 0, 0, 0);
      }

    // ---- prefetch next vertex U/P (idxN has ~arrived; loads hide under L3 phase) ----
    float4 uN0, uN1;
    s8v pN0, pN1, pN2, pN3;
    if (vi < 3) {
      const float* upN = U + (size_t)(v + 1) * 64 + sub * 8;
      uN0 = *reinterpret_cast<const float4*>(upN);
      uN1 = *reinterpret_cast<const float4*>(upN + 4);
      int nb0 = __shfl(idxN, kk0), nb1 = __shfl(idxN, kk1);
      int nb2 = __shfl(idxN, kk2), nb3 = __shfl(idxN, kk3);
      pN0 = *reinterpret_cast<const s8v*>(P + (bbase + (unsigned)nb0) * 64 + sub * 8);
      pN1 = *reinterpret_cast<const s8v*>(P + (bbase + (unsigned)nb1) * 64 + sub * 8);
      pN2 = *reinterpret_cast<const s8v*>(P + (bbase + (unsigned)nb2) * 64 + sub * 8);
      pN3 = *reinterpret_cast<const s8v*>(P + (bbase + (unsigned)nb3) * 64 + sub * 8);
    }

    lds_fence();
    // relu -> H2, nt-interleaved packed b64 stores
#pragma unroll
    for (int mt = 0; mt < 2; ++mt)
#pragma unroll
      for (int i = 0; i < 4; ++i) {
        int m = mt * 16 + q * 4 + i;
        u64 pk = 0;
#pragma unroll
        for (int nt = 0; nt < 4; ++nt) {
          u64 hb = f2bf(fmaxf(acc2[mt][nt][i], 0.0f));
          pk |= hb << (16 * nt);
        }
        *reinterpret_cast<u64*>(&scr[swzi(m, cl * 4, 64)]) = pk;
      }
    lds_fence();

    // ---- layer 3 (s-permuted k-dim) ----
    s8v af3[2][2];
#pragma unroll
    for (int mt = 0; mt < 2; ++mt)
#pragma unroll
      for (int ks = 0; ks < 2; ++ks)
        af3[mt][ks] = *reinterpret_cast<const s8v*>(&scr[swzi(mt * 16 + cl, ks * 32 + q * 8, 64)]);
    f4v acc3[2][4];
#pragma unroll
    for (int mt = 0; mt < 2; ++mt)
#pragma unroll
      for (int nt = 0; nt < 4; ++nt) {
        f4v a0 = {bias3[nt], bias3[nt], bias3[nt], bias3[nt]};
        acc3[mt][nt] = a0;
      }
#pragma unroll
    for (int ks = 0; ks < 2; ++ks)
#pragma unroll
      for (int nt = 0; nt < 4; ++nt) {
        s8v wf = *reinterpret_cast<const s8v*>(&sW3T[swzi(nt * 16 + cl, ks * 32 + q * 8, 64)]);
        acc3[0][nt] = __builtin_amdgcn_mfma_f32_16x16x32_bf16(af3[0][ks], wf, acc3[0][nt], 0, 0, 0);
        acc3[1][nt] = __builtin_amdgcn_mfma_f32_16x16x32_bf16(af3[1][ks], wf, acc3[1][nt], 0, 0, 0);
      }

    float m[4] = {0.0f, 0.0f, 0.0f, 0.0f};
#pragma unroll
    for (int nt = 0; nt < 4; ++nt)
#pragma unroll
      for (int mt = 0; mt < 2; ++mt)
#pragma unroll
        for (int i = 0; i < 4; ++i) m[nt] = fmaxf(m[nt], acc3[mt][nt][i]);
#pragma unroll
    for (int nt = 0; nt < 4; ++nt) {
      m[nt] = fmaxf(m[nt], __shfl_xor(m[nt], 16));
      m[nt] = fmaxf(m[nt], __shfl_xor(m[nt], 32));
    }
    float outv = (q == 0) ? m[0] : (q == 1) ? m[1] : (q == 2) ? m[2] : m[3];
    out[(size_t)v * HDIM + lane] = outv;

    // ---- rotate prefetched state ----
    if (vi < 3) {
      idxC = idxN;
      uC0 = uN0; uC1 = uN1;
      pC0 = pN0; pC1 = pN1; pC2 = pN2; pC3 = pN3;
    }
    lds_fence();  // scr reuse guard for next vertex
  }
}

extern "C" void kernel_launch(void* const* d_in, const int* in_sizes, int n_in,
                              void* d_out, int out_size, void* d_ws, size_t ws_size,
                              hipStream_t stream) {
  const float* x  = (const float*)d_in[0];
  const float* W1 = (const float*)d_in[2];
  const float* b1 = (const float*)d_in[3];
  const float* W2 = (const float*)d_in[4];
  const float* b2 = (const float*)d_in[5];
  const float* W3 = (const float*)d_in[6];
  const float* b3 = (const float*)d_in[7];
  float* out = (float*)d_out;
  int N = in_sizes[0] / FDIM;      // 32768
  int B = in_sizes[1] - 1;         // 16
  int V = N / B;                   // 2048

  char* ws = (char*)d_ws;
  float* sqbuf = (float*)ws;
  size_t off = (size_t)N * sizeof(float);
  int* idxbuf = (int*)(ws + off);
  off += (size_t)N * KNN * sizeof(int);
  off = (off + 255) & ~(size_t)255;
  float* Ubuf = (float*)(ws + off);
  off += (size_t)N * 64 * sizeof(float);
  unsigned short* Pbuf = (unsigned short*)(ws + off);
  off += (size_t)N * 64 * sizeof(unsigned short);
  off = (off + 255) & ~(size_t)255;
  unsigned short* xbfbuf = (unsigned short*)(ws + off);
  off += (size_t)N * 64 * sizeof(unsigned short);
  off = (off + 255) & ~(size_t)255;
  unsigned short* D16buf = (unsigned short*)(ws + off);
  size_t dcap = (ws_size > off) ? (ws_size - off) : 0;
  long long capRows = (long long)(dcap / ((size_t)V * sizeof(unsigned short)));
  capRows &= ~127LL;
  if (capRows > N) capRows = N;
  if (capRows < 128) capRows = 128;  // requires sufficient ws_size

  prep_kernel<<<N / 32, 256, 0, stream>>>(x, xbfbuf, sqbuf);
  uP_kernel<<<N / 128, 256, 0, stream>>>(x, W1, b1, Ubuf, Pbuf);
  for (int R0 = 0; R0 < N; R0 += (int)capRows) {
    int nr = N - R0;
    if (nr > capRows) nr = (int)capRows;
    dim3 g(V / 128, nr / 128);
    dist16_kernel<<<g, 256, 0, stream>>>(xbfbuf, sqbuf, D16buf, R0, V);
    topk16_kernel<<<nr / 4, 256, 0, stream>>>(D16buf, x, sqbuf, idxbuf, R0, nr, V);
  }
  mlp_kernel<<<N / 16, 256, 0, stream>>>(Ubuf, Pbuf, idxbuf, W2, b2, W3, b3, out, V);
}